// Round 5
// baseline (644.192 us; speedup 1.0000x reference)
//
#include <hip/hip_runtime.h>
#include <math.h>

#define B_  4
#define S_  2048
#define D_  1024
#define H_  16
#define DH_ 64
#define DF_ 4096
#define M_  8192   // B*S

// 0.125 (1/sqrt(DH)) * log2(e): folded into Q so softmax = exp2(score)
#define QSC 0.18033688011112042f

typedef __attribute__((ext_vector_type(8))) short bf8_t;   // 8 x bf16 (4 VGPRs)
typedef __attribute__((ext_vector_type(4))) float f4_t;    // 4 x f32

#if defined(__has_builtin)
#if __has_builtin(__builtin_amdgcn_cvt_pk_bf16_f32)
#define HAVE_PKCVT 1
#endif
#if __has_builtin(__builtin_amdgcn_global_load_lds)
#define HAVE_ASYNC 1
#endif
#if __has_builtin(__builtin_amdgcn_exp2f)
#define EXP2F(x) __builtin_amdgcn_exp2f(x)
#else
#define EXP2F(x) __expf((x) * 0.69314718055994531f)
#endif
#else
#define EXP2F(x) __expf((x) * 0.69314718055994531f)
#endif

// pack two f32 -> two bf16 in one u32 (v_cvt_pk_bf16_f32 on gfx950)
__device__ __forceinline__ unsigned pk_bf16(float lo, float hi) {
#ifdef HAVE_PKCVT
  auto r = __builtin_amdgcn_cvt_pk_bf16_f32(lo, hi);
  unsigned u; __builtin_memcpy(&u, &r, 4); return u;
#else
  union { float f; unsigned u; } a, b2; a.f = lo; b2.f = hi;
  unsigned ra = a.u + 0x7fffu + ((a.u >> 16) & 1u);
  unsigned rb = b2.u + 0x7fffu + ((b2.u >> 16) & 1u);
  return (ra >> 16) | (rb & 0xffff0000u);
#endif
}

__device__ __forceinline__ unsigned short f2bf(float x) {
  return (unsigned short)(pk_bf16(x, x) & 0xffffu);
}

__device__ __forceinline__ bf8_t upk8(unsigned u0, unsigned u1, unsigned u2, unsigned u3) {
  union { unsigned u[4]; bf8_t v; } c;
  c.u[0] = u0; c.u[1] = u1; c.u[2] = u2; c.u[3] = u3; return c.v;
}

__device__ __forceinline__ f4_t mfma32(bf8_t a, bf8_t b, f4_t c) {
  return __builtin_amdgcn_mfma_f32_16x16x32_bf16(a, b, c, 0, 0, 0);
}

__device__ __forceinline__ void async16(const void* g, void* l) {
#ifdef HAVE_ASYNC
  __builtin_amdgcn_global_load_lds((__attribute__((address_space(1))) void*)(g),
                                   (__attribute__((address_space(3))) void*)(l), 16, 0, 0);
#else
  *(uint4*)l = *(const uint4*)g;
#endif
}

// XOR swizzle for 64-short (128 B) rows: 16-B chunk c of row r lives at
// physical chunk c ^ (r & 7). Applied on the global source (LDS dest stays
// linear, required by global_load_lds) and on the ds_read address.
__device__ __forceinline__ int sw(int row) { return row & 7; }

// ---------------- weight prep ----------------

// generic fp32 [K][N] -> bf16 [N][K]
__global__ __launch_bounds__(256) void wtrans_kernel(const float* __restrict__ in,
                                                     unsigned short* __restrict__ out,
                                                     int K, int N) {
  const int k0 = blockIdx.x * 32, n0 = blockIdx.y * 32;
  __shared__ float t[32][33];
  const int tid = threadIdx.x;
#pragma unroll
  for (int i = 0; i < 4; i++) {
    int idx = i * 256 + tid; int r = idx >> 5, c = idx & 31;
    t[r][c] = in[(size_t)(k0 + r) * N + n0 + c];
  }
  __syncthreads();
#pragma unroll
  for (int i = 0; i < 4; i++) {
    int idx = i * 256 + tid; int r = idx >> 5, c = idx & 31;
    out[(size_t)(n0 + r) * K + k0 + c] = f2bf(t[c][r]);
  }
}

// Wq/Wk/Wv [H][D][DH] -> WqkvT [3072][1024]  (row n = sel*1024 + h*64 + e, col k = d)
__global__ __launch_bounds__(256) void qkvpack_kernel(const float* __restrict__ Wq,
                                                      const float* __restrict__ Wk,
                                                      const float* __restrict__ Wv,
                                                      unsigned short* __restrict__ WqkvT) {
  const int z = blockIdx.z;            // 0..47
  const int sel = z >> 4, h = z & 15;
  const float* in = (sel == 0 ? Wq : sel == 1 ? Wk : Wv) + (size_t)h * D_ * DH_;
  const int k0 = blockIdx.x * 32, n0 = blockIdx.y * 32;   // k over D, n over DH
  __shared__ float t[32][33];
  const int tid = threadIdx.x;
#pragma unroll
  for (int i = 0; i < 4; i++) {
    int idx = i * 256 + tid; int r = idx >> 5, c = idx & 31;
    t[r][c] = in[(size_t)(k0 + r) * DH_ + n0 + c];
  }
  __syncthreads();
#pragma unroll
  for (int i = 0; i < 4; i++) {
    int idx = i * 256 + tid; int r = idx >> 5, c = idx & 31;
    int n = sel * 1024 + h * 64 + n0 + r;
    WqkvT[(size_t)n * D_ + k0 + c] = f2bf(t[c][r]);
  }
}

__global__ void biaspack_kernel(const float* __restrict__ bq, const float* __restrict__ bk,
                                const float* __restrict__ bv, float* __restrict__ bqkv) {
  int i = blockIdx.x * 256 + threadIdx.x;
  if (i < 3072) {
    int sel = i >> 10, j = i & 1023;
    const float* src = sel == 0 ? bq : sel == 1 ? bk : bv;
    bqkv[i] = src[j];
  }
}

// ---------------- layernorm (fp32 in -> bf16 out) ----------------

__global__ __launch_bounds__(256) void ln_kernel(const float* __restrict__ x,
                                                 const float* __restrict__ w,
                                                 const float* __restrict__ bb,
                                                 unsigned short* __restrict__ out) {
  const int row = blockIdx.x;
  const float* xr = x + (size_t)row * D_;
  const int tid = threadIdx.x;
  float v[4]; float s = 0.f;
#pragma unroll
  for (int i = 0; i < 4; i++) { v[i] = xr[tid + i * 256]; s += v[i]; }
  __shared__ float red[8];
#pragma unroll
  for (int o = 32; o; o >>= 1) s += __shfl_xor(s, o, 64);
  const int wv = tid >> 6, ln = tid & 63;
  if (!ln) red[wv] = s;
  __syncthreads();
  float mean = (red[0] + red[1] + red[2] + red[3]) * (1.f / 1024.f);
  float s2 = 0.f;
#pragma unroll
  for (int i = 0; i < 4; i++) { float d = v[i] - mean; s2 += d * d; }
#pragma unroll
  for (int o = 32; o; o >>= 1) s2 += __shfl_xor(s2, o, 64);
  if (!ln) red[4 + wv] = s2;
  __syncthreads();
  float var = (red[4] + red[5] + red[6] + red[7]) * (1.f / 1024.f);
  float rstd = rsqrtf(var + 1e-5f);
#pragma unroll
  for (int i = 0; i < 4; i++) {
    int c = tid + i * 256;
    out[(size_t)row * D_ + c] = f2bf((v[i] - mean) * rstd * w[c] + bb[c]);
  }
}

// FFN2 split-K combine: out = out(z1 partial) + P(z0 partial) + resid + bias
__global__ __launch_bounds__(256) void ffn2red_kernel(float* __restrict__ out,
                                                      const float* __restrict__ P,
                                                      const float* __restrict__ resid,
                                                      const float* __restrict__ bias) {
  const size_t i = ((size_t)blockIdx.x * 256 + threadIdx.x) * 4;
  f4_t a  = *(const f4_t*)&out[i];
  f4_t p  = *(const f4_t*)&P[i];
  f4_t rr = *(const f4_t*)&resid[i];
  f4_t bb = *(const f4_t*)&bias[(int)(i & 1023)];
  *(f4_t*)&out[i] = a + p + rr + bb;
}

// ---------------- GEMM 128x128 (proven m97 structure) ----------------
// Used for the Wo GEMM (N=1024, K=1024). T1 XCD-bijective block swizzle
// (nwg = 512, % 8 == 0).
template <int EPI>
__global__ __launch_bounds__(256) void gemm_bt(const unsigned short* __restrict__ A,
                                               const unsigned short* __restrict__ Bt,
                                               const float* __restrict__ bias,
                                               const float* __restrict__ resid,
                                               unsigned short* __restrict__ outb,
                                               float* __restrict__ outf,
                                               int Ndim, int Kdim) {
  __shared__ __align__(16) unsigned short Asmem[4096];   // [128][32]
  __shared__ __align__(16) unsigned short Bsmem[4096];   // [128][32]
  const int tid = threadIdx.x;
  const int wave = tid >> 6, lane = tid & 63;
  const int quad = lane >> 4, l16 = lane & 15;
  const int wm = wave >> 1, wn = wave & 1;

  // XCD-bijective block swizzle
  const int gx = gridDim.x;
  const int nwg = gx * (int)gridDim.y;
  const int lin = (int)blockIdx.y * gx + (int)blockIdx.x;
  const int swz = (lin & 7) * (nwg >> 3) + (lin >> 3);
  const int m0 = (swz / gx) * 128, n0 = (swz % gx) * 128;

  const f4_t fzero = {0.f, 0.f, 0.f, 0.f};
  f4_t acc[4][4];
#pragma unroll
  for (int i = 0; i < 4; i++)
#pragma unroll
    for (int j = 0; j < 4; j++) acc[i][j] = fzero;

  const int rowA = tid >> 2;            // 0..63
  const int kp = (tid & 3) * 8;         // 0,8,16,24

  for (int k0 = 0; k0 < Kdim; k0 += 32) {
    __syncthreads();
#pragma unroll
    for (int r = 0; r < 2; r++) {
      const int row = r * 64 + rowA;
      const int e = row * 32 + kp;
      async16(A  + (size_t)(m0 + row) * Kdim + k0 + kp, &Asmem[e]);
      async16(Bt + (size_t)(n0 + row) * Kdim + k0 + kp, &Bsmem[e]);
    }
    __syncthreads();

    bf8_t a[4], b[4];
#pragma unroll
    for (int i = 0; i < 4; i++) {
      a[i] = *(const bf8_t*)&Asmem[(wm * 64 + i * 16 + l16) * 32 + quad * 8];
      b[i] = *(const bf8_t*)&Bsmem[(wn * 64 + i * 16 + l16) * 32 + quad * 8];
    }
#pragma unroll
    for (int i = 0; i < 4; i++)
#pragma unroll
      for (int j = 0; j < 4; j++)
        acc[i][j] = mfma32(a[i], b[j], acc[i][j]);
  }

#pragma unroll
  for (int i = 0; i < 4; i++) {
#pragma unroll
    for (int j = 0; j < 4; j++) {
#pragma unroll
      for (int r = 0; r < 4; r++) {
        const int m = m0 + wm * 64 + i * 16 + quad * 4 + r;
        const int n = n0 + wn * 64 + j * 16 + l16;
        float v = acc[i][j][r] + bias[n];
        if constexpr (EPI == 2) v = 0.5f * v * (1.f + erff(v * 0.70710678118654752f));
        if constexpr (EPI == 1) {
          v += resid[(size_t)m * Ndim + n];
          outf[(size_t)m * Ndim + n] = v;
        } else {
          outb[(size_t)m * Ndim + n] = f2bf(v);
        }
      }
    }
  }
}

// ---------------- GEMM 256x256, counted-wait overlap (v3) ----------------
// 256x256 tile, BK=64, 8 waves (2M x 4N), per-wave 128x64 output (8x4 frags).
// Per K-tile: issue all 24 ds_reads (ks0 block, then ks1 block) -> 32 ks0
// MFMAs (counted lgkmcnt: ks1's LDS drain overlaps the ks0 burst) ->
// lgkmcnt(0)+barrier -> stage full tile t+2 into buf t&1 -> 32 ks1 MFMAs ->
// counted vmcnt(8) -> barrier. 2 barriers/K-tile.
template <int EPI>
__global__ __launch_bounds__(512, 2) void gemm256(const unsigned short* __restrict__ A,
                                                  const unsigned short* __restrict__ Bt,
                                                  const float* __restrict__ bias,
                                                  const float* __restrict__ resid,
                                                  unsigned short* __restrict__ outb,
                                                  float* __restrict__ outf,
                                                  float* __restrict__ outf2,
                                                  unsigned short* __restrict__ vTout,
                                                  int Ndim, int Kdim, int Kstride) {
  __shared__ __align__(16) unsigned short Asm[32768];   // [2 buf][256 rows][64 k]
  __shared__ __align__(16) unsigned short Bsm[32768];
  const int tid = threadIdx.x;
  const int wave = tid >> 6, lane = tid & 63;
  const int quad = lane >> 4, l16 = lane & 15;
  const int wm = wave >> 2, wn = wave & 3;

  // XCD-bijective block swizzle over (x,y); z is the K-split index
  const int gx = gridDim.x;
  const int nwg = gx * (int)gridDim.y;
  const int lin = (int)blockIdx.y * gx + (int)blockIdx.x;
  const int swz = (lin & 7) * (nwg >> 3) + (lin >> 3);
  const int m0 = (swz / gx) * 256, n0 = (swz % gx) * 256;
  const int kz = (int)blockIdx.z * Kdim;

  const int NT = Kdim >> 6;
  const int srow = lane >> 3, schk = lane & 7;   // stage: lane = 8*subrow + chunk

#define STAGE_A(t, row0) do {                                               \
    const int r_ = (row0) + srow;                                           \
    async16(A + (size_t)(m0 + r_) * Kstride + kz + (t) * 64 +               \
                ((schk ^ (r_ & 7)) << 3),                                   \
            &Asm[(((t) & 1) << 14) + ((row0) << 6)]); } while (0)
#define STAGE_B(t, row0) do {                                               \
    const int r_ = (row0) + srow;                                           \
    async16(Bt + (size_t)(n0 + r_) * Kstride + kz + (t) * 64 +              \
                 ((schk ^ (r_ & 7)) << 3),                                  \
            &Bsm[(((t) & 1) << 14) + ((row0) << 6)]); } while (0)
#define STAGE_FULL(t) do {                                                  \
    STAGE_A(t, wave * 8);       STAGE_A(t, 64 + wave * 8);                  \
    STAGE_A(t, 128 + wave * 8); STAGE_A(t, 192 + wave * 8);                 \
    STAGE_B(t, wave * 8);       STAGE_B(t, 64 + wave * 8);                  \
    STAGE_B(t, 128 + wave * 8); STAGE_B(t, 192 + wave * 8); } while (0)

#define AFR(bo, row, s) \
  (*(const bf8_t*)&Asm[(bo) + ((row) << 6) + ((((s) * 4 + quad) ^ ((row) & 7)) << 3)])
#define BFR(bo, row, s) \
  (*(const bf8_t*)&Bsm[(bo) + ((row) << 6) + ((((s) * 4 + quad) ^ ((row) & 7)) << 3)])

  const f4_t fzero = {0.f, 0.f, 0.f, 0.f};
  f4_t acc[8][4];
#pragma unroll
  for (int i = 0; i < 8; i++)
#pragma unroll
    for (int j = 0; j < 4; j++) acc[i][j] = fzero;

  STAGE_FULL(0);
  STAGE_FULL(1);
  asm volatile("s_waitcnt vmcnt(8)" ::: "memory");
  __builtin_amdgcn_s_barrier();

  const int ar0 = wm << 7;   // wave A base row (local)
  const int br0 = wn << 6;   // wave B base row (local)

  for (int t = 0; t < NT; ++t) {
    const int bo = (t & 1) << 14;
    const bool pf = (t + 2) < NT;
    const int t2 = t + 2;
    bf8_t a0[8], b0[4], a1[8], b1[4];

#pragma unroll
    for (int i = 0; i < 8; i++) a0[i] = AFR(bo, ar0 + i * 16 + l16, 0);
#pragma unroll
    for (int j = 0; j < 4; j++) b0[j] = BFR(bo, br0 + j * 16 + l16, 0);
#pragma unroll
    for (int i = 0; i < 8; i++) a1[i] = AFR(bo, ar0 + i * 16 + l16, 1);
#pragma unroll
    for (int j = 0; j < 4; j++) b1[j] = BFR(bo, br0 + j * 16 + l16, 1);

    __builtin_amdgcn_s_setprio(1);
#pragma unroll
    for (int i = 0; i < 8; i++)
#pragma unroll
      for (int j = 0; j < 4; j++)
        acc[i][j] = mfma32(a0[i], b0[j], acc[i][j]);
    __builtin_amdgcn_s_setprio(0);

    asm volatile("s_waitcnt lgkmcnt(0)" ::: "memory");
    __builtin_amdgcn_s_barrier();

    if (pf) STAGE_FULL(t2);

    __builtin_amdgcn_s_setprio(1);
#pragma unroll
    for (int i = 0; i < 8; i++)
#pragma unroll
      for (int j = 0; j < 4; j++)
        acc[i][j] = mfma32(a1[i], b1[j], acc[i][j]);
    __builtin_amdgcn_s_setprio(0);

    if (pf) asm volatile("s_waitcnt vmcnt(8)" ::: "memory");
    else    asm volatile("s_waitcnt vmcnt(0)" ::: "memory");
    __builtin_amdgcn_s_barrier();
  }

#undef STAGE_A
#undef STAGE_B
#undef STAGE_FULL
#undef AFR
#undef BFR

  // ---------------- epilogues ----------------
  if (EPI == 0 && n0 >= 2048) {
    // V region -> vT[(b*16+h)*64+e][ (s&~63) + g(s&63) ], 4 consecutive t per lane
    const int bb2 = m0 >> 11;                      // batch (tile never crosses)
    const int sb64 = (m0 & 2047) + (wm << 7);      // 64-aligned base
#pragma unroll
    for (int mi = 0; mi < 8; mi++) {
      const int i4 = mi & 3;
      const int g0 = (i4 & 2) * 16 + 8 * quad + 4 * (i4 & 1);
      const int sbase = sb64 + (mi >> 2) * 64 + g0;
#pragma unroll
      for (int nj = 0; nj < 4; nj++) {
        const int n = n0 + wn * 64 + nj * 16 + l16;
        const int ef = n - 2048;
        const int hh = ef >> 6, e = ef & 63;
        const float bsv = bias[n];
        uint2 wq;
        wq.x = pk_bf16(acc[mi][nj][0] + bsv, acc[mi][nj][1] + bsv);
        wq.y = pk_bf16(acc[mi][nj][2] + bsv, acc[mi][nj][3] + bsv);
        *(uint2*)&vTout[(size_t)((bb2 * 16 + hh) * 64 + e) * S_ + sbase] = wq;
      }
    }
    return;
  }

  float* const pdst = (EPI == 3) ? (blockIdx.z ? outf2 : outf) : outf;
  const float sc = (EPI == 0 && n0 < 1024) ? QSC : 1.f;
#pragma unroll
  for (int mi = 0; mi < 8; mi++) {
#pragma unroll
    for (int nj = 0; nj < 4; nj++) {
      const int n = n0 + wn * 64 + nj * 16 + l16;
      const float bs = (EPI == 3) ? 0.f : bias[n];
#pragma unroll
      for (int r = 0; r < 4; r++) {
        const int m = m0 + wm * 128 + mi * 16 + quad * 4 + r;
        float v = acc[mi][nj][r] + bs;
        if constexpr (EPI == 0) v *= sc;
        if constexpr (EPI == 2) v = 0.5f * v * (1.f + erff(v * 0.70710678118654752f));
        if constexpr (EPI == 1) {
          v += resid[(size_t)m * Ndim + n];
          outf[(size_t)m * Ndim + n] = v;
        } else if constexpr (EPI == 3) {
          pdst[(size_t)m * Ndim + n] = v;
        } else {
          outb[(size_t)m * Ndim + n] = f2bf(v);
        }
      }
    }
  }
}

// ---------------- flash attention (v2: dbuf K/V + counted vmcnt) ----------------
// 256 threads (4 waves), 128 q-rows/block; wave owns 32 s as 2x16 blocks.
// S^T = mfma(A=K, B=Q) -> P exits QK^T in PV B-operand layout -> PV pure mfma32.
// v2: K/V double-buffered in LDS (72 KB total, 2 blocks/CU); per tile:
// raw-barrier -> stage tile t+1 (8 async16) -> counted vmcnt(8) -> raw-barrier
// -> compute tile t. Tile t's loads were issued one full tile earlier; the
// in-loop wait never drains to 0 (v1 used __syncthreads = vmcnt(0) drain per
// tile, exposing full HBM latency 16x). Mask -> bias table precomputed in LDS
// once (no per-tile VM loads -> counted vmcnt stays exact). XCD-chunked block
// swizzle: each XCD gets 8 consecutive bh (all 16 q-blocks) -> K/V L2-resident.

__global__ __launch_bounds__(256, 2) void attn_kernel(const unsigned short* __restrict__ qkv,
                                                      const unsigned short* __restrict__ vT,
                                                      const int* __restrict__ maskp,
                                                      unsigned short* __restrict__ attended) {
  const int tid = threadIdx.x, wv = tid >> 6, lane = tid & 63;
  const int quad = lane >> 4, l16 = lane & 15;

  // XCD-chunked swizzle (bijective on 1024 blocks): XCD x = lin%8 owns virt
  // [x*128, x*128+128) = 8 bh x 16 q-blocks, q-block fastest.
  const int lin = (int)blockIdx.y * (int)gridDim.x + (int)blockIdx.x;
  const int virt = (lin & 7) * 128 + (lin >> 3);
  const int q0 = (virt & 15) * 128;
  const int bh = virt >> 4, b = bh >> 4, h = bh & 15;

  __shared__ __align__(16) unsigned short KsmF[16384];   // [2 buf][128 t][64 e]
  __shared__ __align__(16) unsigned short VsmF[16384];   // [2 buf][64 e][128 t]
  __shared__ float biasf[2048];                          // mask bias, whole row

  // mask -> bias floats once (2048 ints, 8 per thread)
  {
    const int4 mk0 = *(const int4*)&maskp[b * S_ + tid * 8];
    const int4 mk1 = *(const int4*)&maskp[b * S_ + tid * 8 + 4];
    f4_t bv0, bv1;
    bv0[0] = mk0.x ? 0.f : -8e9f; bv0[1] = mk0.y ? 0.f : -8e9f;
    bv0[2] = mk0.z ? 0.f : -8e9f; bv0[3] = mk0.w ? 0.f : -8e9f;
    bv1[0] = mk1.x ? 0.f : -8e9f; bv1[1] = mk1.y ? 0.f : -8e9f;
    bv1[2] = mk1.z ? 0.f : -8e9f; bv1[3] = mk1.w ? 0.f : -8e9f;
    *(f4_t*)&biasf[tid * 8] = bv0;
    *(f4_t*)&biasf[tid * 8 + 4] = bv1;
  }

// stage K/V tile it into buffer cb: 8 async16 per thread, linear LDS dest,
// inverse-swizzled global source (chunk ^ row&7).
#define STAGE_T(it, cb) do {                                                   \
    _Pragma("unroll")                                                          \
    for (int r_ = 0; r_ < 4; r_++) {                                           \
      const int cc = r_ * 256 + tid;                                           \
      const int krow = cc >> 3, kc = (cc & 7) ^ (krow & 7);                    \
      async16(qkv + (size_t)(b * S_ + (it) * 128 + krow) * 3072 + 1024 +       \
                  h * 64 + kc * 8,                                             \
              &KsmF[((cb) << 13) + cc * 8]);                                   \
      const int e_ = cc >> 4, hf = (cc >> 3) & 1, vc = (cc & 7) ^ (e_ & 7);    \
      async16(vT + (size_t)(bh * 64 + e_) * S_ + (it) * 128 + hf * 64 +        \
                  vc * 8,                                                      \
              &VsmF[((cb) << 13) + cc * 8]);                                   \
    } } while (0)

  // Q fragments straight from global (one-time; B-operand layout k=quad*8+j)
  bf8_t aq[2][2];
#pragma unroll
  for (int sb = 0; sb < 2; sb++) {
    const unsigned short* qrow =
        qkv + (size_t)(b * S_ + q0 + wv * 32 + sb * 16 + l16) * 3072 + h * 64;
    aq[sb][0] = *(const bf8_t*)(qrow + quad * 8);
    aq[sb][1] = *(const bf8_t*)(qrow + 32 + quad * 8);
  }

  const bf8_t ones8 = {0x3F80, 0x3F80, 0x3F80, 0x3F80, 0x3F80, 0x3F80, 0x3F80, 0x3F80};
  const f4_t fzero = {0.f, 0.f, 0.f, 0.f};
  f4_t o[2][4], lacc[2];
#pragma unroll
  for (int sb = 0; sb < 2; sb++) {
    lacc[sb] = fzero;
#pragma unroll
    for (int ee = 0; ee < 4; ee++) o[sb][ee] = fzero;
  }

  // prologue: stage tile 0 (mask loads above are older; compiler waits only
  // for them where used); bias writes visible after lgkmcnt(0)+barrier.
  STAGE_T(0, 0);
  asm volatile("s_waitcnt lgkmcnt(0)" ::: "memory");
  __builtin_amdgcn_s_barrier();

  for (int it = 0; it < S_ / 128; ++it) {
    const int cb = it & 1;
    // all waves done reading buf cb^1 (tile it-1) -> safe to overwrite
    __builtin_amdgcn_s_barrier();
    if (it + 1 < S_ / 128) {
      STAGE_T(it + 1, cb ^ 1);
      asm volatile("s_waitcnt vmcnt(8)" ::: "memory");   // tile it landed; t+1 in flight
    } else {
      asm volatile("s_waitcnt vmcnt(0)" ::: "memory");
    }
    __builtin_amdgcn_s_barrier();   // every wave's tile-it loads landed

#pragma unroll
    for (int th = 0; th < 2; th++) {
      // S^T: sf[sb][jj][r] = score^T[t=th*64+16jj+4quad+r][s=block+l16] + maskbias
      f4_t sf[2][4];
#pragma unroll
      for (int jj = 0; jj < 4; jj++) {
        f4_t bi = *(const f4_t*)&biasf[it * 128 + th * 64 + jj * 16 + quad * 4];
        sf[0][jj] = bi;
        sf[1][jj] = bi;
      }
      __builtin_amdgcn_s_setprio(1);
#pragma unroll
      for (int jj = 0; jj < 4; jj++) {
        const int krow = th * 64 + jj * 16 + l16, sk = krow & 7;
        bf8_t kf0 = *(const bf8_t*)&KsmF[(cb << 13) + krow * 64 + ((quad ^ sk) << 3)];
        bf8_t kf1 = *(const bf8_t*)&KsmF[(cb << 13) + krow * 64 + (((quad + 4) ^ sk) << 3)];
        sf[0][jj] = mfma32(kf0, aq[0][0], sf[0][jj]);
        sf[0][jj] = mfma32(kf1, aq[0][1], sf[0][jj]);
        sf[1][jj] = mfma32(kf0, aq[1][0], sf[1][jj]);
        sf[1][jj] = mfma32(kf1, aq[1][1], sf[1][jj]);
      }
      __builtin_amdgcn_s_setprio(0);

      // p = exp2(sf); pack straight into K=32 B-frags
      bf8_t pp[2][2];
#pragma unroll
      for (int sb = 0; sb < 2; sb++) {
#pragma unroll
        for (int h2 = 0; h2 < 2; h2++) {
          float p0 = EXP2F(sf[sb][2 * h2][0]),     p1 = EXP2F(sf[sb][2 * h2][1]);
          float p2 = EXP2F(sf[sb][2 * h2][2]),     p3 = EXP2F(sf[sb][2 * h2][3]);
          float p4 = EXP2F(sf[sb][2 * h2 + 1][0]), p5 = EXP2F(sf[sb][2 * h2 + 1][1]);
          float p6 = EXP2F(sf[sb][2 * h2 + 1][2]), p7 = EXP2F(sf[sb][2 * h2 + 1][3]);
          pp[sb][h2] = upk8(pk_bf16(p0, p1), pk_bf16(p2, p3),
                            pk_bf16(p4, p5), pk_bf16(p6, p7));
        }
        lacc[sb] = mfma32(ones8, pp[sb][0], lacc[sb]);
        lacc[sb] = mfma32(ones8, pp[sb][1], lacc[sb]);
      }

      // O^T += V^T x P^T: pure K=32 MFMAs, V-frags single b128 (reused across sb)
      __builtin_amdgcn_s_setprio(1);
#pragma unroll
      for (int ee = 0; ee < 4; ee++) {
        const int vrow = ee * 16 + l16, sv = vrow & 7;
#pragma unroll
        for (int h2 = 0; h2 < 2; h2++) {
          bf8_t vf = *(const bf8_t*)&VsmF[(cb << 13) + vrow * 128 +
                                          (((4 * h2 + quad) ^ sv) << 3)
                                          + th * 64];
          o[0][ee] = mfma32(vf, pp[0][h2], o[0][ee]);
          o[1][ee] = mfma32(vf, pp[1][h2], o[1][ee]);
        }
      }
      __builtin_amdgcn_s_setprio(0);
    }
  }

#undef STAGE_T

  float linv[2];
#pragma unroll
  for (int sb = 0; sb < 2; sb++) linv[sb] = 1.f / lacc[sb][0];

  // transpose O^T -> row-major via LDS overlay (pad 72), coalesced 16-B stores
  __syncthreads();                       // last tile's readers done before overlay
#pragma unroll
  for (int sb = 0; sb < 2; sb++) {
    int srow = wv * 32 + sb * 16 + l16;
#pragma unroll
    for (int ee = 0; ee < 4; ee++) {
      unsigned w0 = pk_bf16(o[sb][ee][0] * linv[sb], o[sb][ee][1] * linv[sb]);
      unsigned w1 = pk_bf16(o[sb][ee][2] * linv[sb], o[sb][ee][3] * linv[sb]);
      uint2 wq; wq.x = w0; wq.y = w1;
      *(uint2*)&KsmF[srow * 72 + ee * 16 + quad * 4] = wq;
    }
  }
  __syncthreads();
#pragma unroll
  for (int it = 0; it < 4; it++) {
    int row = it * 32 + (tid >> 3), e0 = (tid & 7) * 8;
    bf8_t v = *(const bf8_t*)&KsmF[row * 72 + e0];
    *(bf8_t*)&attended[(size_t)(b * S_ + q0 + row) * D_ + h * 64 + e0] = v;
  }
}

// ---------------- launcher ----------------

extern "C" void kernel_launch(void* const* d_in, const int* in_sizes, int n_in,
                              void* d_out, int out_size, void* d_ws, size_t ws_size,
                              hipStream_t stream) {
  const float* state = (const float*)d_in[0];
  const int*   maskp = (const int*)d_in[1];
  const float* ln1w  = (const float*)d_in[2];
  const float* ln1b  = (const float*)d_in[3];
  const float* Wq    = (const float*)d_in[4];
  const float* bq    = (const float*)d_in[5];
  const float* Wk    = (const float*)d_in[6];
  const float* bk    = (const float*)d_in[7];
  const float* Wv    = (const float*)d_in[8];
  const float* bv    = (const float*)d_in[9];
  const float* Wo    = (const float*)d_in[10];
  const float* bo    = (const float*)d_in[11];
  const float* ln2w  = (const float*)d_in[12];
  const float* ln2b  = (const float*)d_in[13];
  const float* W1    = (const float*)d_in[14];
  const float* b1    = (const float*)d_in[15];
  const float* W2    = (const float*)d_in[16];
  const float* b2    = (const float*)d_in[17];

  // workspace carve-up (total ~136 MiB).
  // {hidden, WqkvT, WoT, W1T} form a contiguous 32 MiB block dead by FFN2
  // time -> aliased as the split-K f32 partial buffer P. ff1 aliases the
  // dead qkv+vT region (64 MiB).
  char* w = (char*)d_ws;
  unsigned short* hidden = (unsigned short*)w; w += (size_t)M_ * D_ * 2;      // 16 MiB
  unsigned short* WqkvT  = (unsigned short*)w; w += (size_t)3072 * D_ * 2;    //  6 MiB
  unsigned short* WoT    = (unsigned short*)w; w += (size_t)D_ * D_ * 2;      //  2 MiB
  unsigned short* W1T    = (unsigned short*)w; w += (size_t)DF_ * D_ * 2;     //  8 MiB
  unsigned short* qkv    = (unsigned short*)w; w += (size_t)M_ * 3072 * 2;    // 48 MiB
  unsigned short* vT     = (unsigned short*)w; w += (size_t)M_ * D_ * 2;      // 16 MiB
  float*          outp   = (float*)w;          w += (size_t)M_ * D_ * 4;      // 32 MiB
  unsigned short* W2T    = (unsigned short*)w; w += (size_t)D_ * DF_ * 2;     //  8 MiB
  float*          bqkv   = (float*)w;          w += 3072 * 4;
  unsigned short* ff1    = qkv;                // 64 MiB alias (qkv+vT dead before FFN1)
  float*          Pbuf   = (float*)hidden;     // 32 MiB alias (dead before FFN2)

  // weight prep
  qkvpack_kernel<<<dim3(32, 2, 48), 256, 0, stream>>>(Wq, Wk, Wv, WqkvT);
  wtrans_kernel<<<dim3(32, 32), 256, 0, stream>>>(Wo, WoT, D_, D_);
  wtrans_kernel<<<dim3(32, 128), 256, 0, stream>>>(W1, W1T, D_, DF_);
  wtrans_kernel<<<dim3(128, 32), 256, 0, stream>>>(W2, W2T, DF_, D_);
  biaspack_kernel<<<12, 256, 0, stream>>>(bq, bk, bv, bqkv);

  // attention block (V transposed into vT by the QKV epilogue)
  ln_kernel<<<M_, 256, 0, stream>>>(state, ln1w, ln1b, hidden);
  gemm256<0><<<dim3(3072 / 256, M_ / 256), 512, 0, stream>>>(
      hidden, WqkvT, bqkv, nullptr, qkv, nullptr, nullptr, vT, 3072, D_, D_);
  attn_kernel<<<dim3(S_ / 128, B_ * H_), 256, 0, stream>>>(qkv, vT, maskp, hidden);
  gemm_bt<1><<<dim3(D_ / 128, M_ / 128), 256, 0, stream>>>(hidden, WoT, bo, state,
                                                           nullptr, outp, D_, D_);
  // FFN block
  ln_kernel<<<M_, 256, 0, stream>>>(outp, ln2w, ln2b, hidden);
  gemm256<2><<<dim3(DF_ / 256, M_ / 256), 512, 0, stream>>>(
      hidden, W1T, b1, nullptr, ff1, nullptr, nullptr, nullptr, DF_, D_, D_);
  // FFN2: split-K=2 over z (full-GPU 256 blocks); z0 -> Pbuf, z1 -> d_out (raw),
  // then combine with resid + bias.
  gemm256<3><<<dim3(D_ / 256, M_ / 256, 2), 512, 0, stream>>>(
      ff1, W2T, nullptr, nullptr, nullptr, Pbuf, (float*)d_out, nullptr,
      D_, DF_ / 2, DF_);
  ffn2red_kernel<<<(M_ * D_) / 1024, 256, 0, stream>>>((float*)d_out, Pbuf, outp, b2);
}

// Round 6
// 537.710 us; speedup vs baseline: 1.1980x; 1.1980x over previous
//
#include <hip/hip_runtime.h>
#include <math.h>

#define B_  4
#define S_  2048
#define D_  1024
#define H_  16
#define DH_ 64
#define DF_ 4096
#define M_  8192   // B*S

// 0.125 (1/sqrt(DH)) * log2(e): folded into Q so softmax = exp2(score)
#define QSC 0.18033688011112042f

typedef __attribute__((ext_vector_type(8))) short bf8_t;   // 8 x bf16 (4 VGPRs)
typedef __attribute__((ext_vector_type(4))) float f4_t;    // 4 x f32

#if defined(__has_builtin)
#if __has_builtin(__builtin_amdgcn_cvt_pk_bf16_f32)
#define HAVE_PKCVT 1
#endif
#if __has_builtin(__builtin_amdgcn_global_load_lds)
#define HAVE_ASYNC 1
#endif
#if __has_builtin(__builtin_amdgcn_exp2f)
#define EXP2F(x) __builtin_amdgcn_exp2f(x)
#else
#define EXP2F(x) __expf((x) * 0.69314718055994531f)
#endif
#else
#define EXP2F(x) __expf((x) * 0.69314718055994531f)
#endif

#define SBAR() __builtin_amdgcn_sched_barrier(0)

// pack two f32 -> two bf16 in one u32 (v_cvt_pk_bf16_f32 on gfx950)
__device__ __forceinline__ unsigned pk_bf16(float lo, float hi) {
#ifdef HAVE_PKCVT
  auto r = __builtin_amdgcn_cvt_pk_bf16_f32(lo, hi);
  unsigned u; __builtin_memcpy(&u, &r, 4); return u;
#else
  union { float f; unsigned u; } a, b2; a.f = lo; b2.f = hi;
  unsigned ra = a.u + 0x7fffu + ((a.u >> 16) & 1u);
  unsigned rb = b2.u + 0x7fffu + ((b2.u >> 16) & 1u);
  return (ra >> 16) | (rb & 0xffff0000u);
#endif
}

__device__ __forceinline__ unsigned short f2bf(float x) {
  return (unsigned short)(pk_bf16(x, x) & 0xffffu);
}

__device__ __forceinline__ bf8_t upk8(unsigned u0, unsigned u1, unsigned u2, unsigned u3) {
  union { unsigned u[4]; bf8_t v; } c;
  c.u[0] = u0; c.u[1] = u1; c.u[2] = u2; c.u[3] = u3; return c.v;
}

__device__ __forceinline__ f4_t mfma32(bf8_t a, bf8_t b, f4_t c) {
  return __builtin_amdgcn_mfma_f32_16x16x32_bf16(a, b, c, 0, 0, 0);
}

__device__ __forceinline__ void async16(const void* g, void* l) {
#ifdef HAVE_ASYNC
  __builtin_amdgcn_global_load_lds((__attribute__((address_space(1))) void*)(g),
                                   (__attribute__((address_space(3))) void*)(l), 16, 0, 0);
#else
  *(uint4*)l = *(const uint4*)g;
#endif
}

// XOR swizzle for 64-short (128 B) rows: 16-B chunk c of row r lives at
// physical chunk c ^ (r & 7). Applied on the global source (LDS dest stays
// linear, required by global_load_lds) and on the ds_read address.
__device__ __forceinline__ int sw(int row) { return row & 7; }

// ---------------- weight prep ----------------

// generic fp32 [K][N] -> bf16 [N][K]
__global__ __launch_bounds__(256) void wtrans_kernel(const float* __restrict__ in,
                                                     unsigned short* __restrict__ out,
                                                     int K, int N) {
  const int k0 = blockIdx.x * 32, n0 = blockIdx.y * 32;
  __shared__ float t[32][33];
  const int tid = threadIdx.x;
#pragma unroll
  for (int i = 0; i < 4; i++) {
    int idx = i * 256 + tid; int r = idx >> 5, c = idx & 31;
    t[r][c] = in[(size_t)(k0 + r) * N + n0 + c];
  }
  __syncthreads();
#pragma unroll
  for (int i = 0; i < 4; i++) {
    int idx = i * 256 + tid; int r = idx >> 5, c = idx & 31;
    out[(size_t)(n0 + r) * K + k0 + c] = f2bf(t[c][r]);
  }
}

// Wq/Wk/Wv [H][D][DH] -> WqkvT [3072][1024]  (row n = sel*1024 + h*64 + e, col k = d)
__global__ __launch_bounds__(256) void qkvpack_kernel(const float* __restrict__ Wq,
                                                      const float* __restrict__ Wk,
                                                      const float* __restrict__ Wv,
                                                      unsigned short* __restrict__ WqkvT) {
  const int z = blockIdx.z;            // 0..47
  const int sel = z >> 4, h = z & 15;
  const float* in = (sel == 0 ? Wq : sel == 1 ? Wk : Wv) + (size_t)h * D_ * DH_;
  const int k0 = blockIdx.x * 32, n0 = blockIdx.y * 32;   // k over D, n over DH
  __shared__ float t[32][33];
  const int tid = threadIdx.x;
#pragma unroll
  for (int i = 0; i < 4; i++) {
    int idx = i * 256 + tid; int r = idx >> 5, c = idx & 31;
    t[r][c] = in[(size_t)(k0 + r) * DH_ + n0 + c];
  }
  __syncthreads();
#pragma unroll
  for (int i = 0; i < 4; i++) {
    int idx = i * 256 + tid; int r = idx >> 5, c = idx & 31;
    int n = sel * 1024 + h * 64 + n0 + r;
    WqkvT[(size_t)n * D_ + k0 + c] = f2bf(t[c][r]);
  }
}

__global__ void biaspack_kernel(const float* __restrict__ bq, const float* __restrict__ bk,
                                const float* __restrict__ bv, float* __restrict__ bqkv) {
  int i = blockIdx.x * 256 + threadIdx.x;
  if (i < 3072) {
    int sel = i >> 10, j = i & 1023;
    const float* src = sel == 0 ? bq : sel == 1 ? bk : bv;
    bqkv[i] = src[j];
  }
}

// ---------------- layernorm (fp32 in -> bf16 out) ----------------

__global__ __launch_bounds__(256) void ln_kernel(const float* __restrict__ x,
                                                 const float* __restrict__ w,
                                                 const float* __restrict__ bb,
                                                 unsigned short* __restrict__ out) {
  const int row = blockIdx.x;
  const float* xr = x + (size_t)row * D_;
  const int tid = threadIdx.x;
  float v[4]; float s = 0.f;
#pragma unroll
  for (int i = 0; i < 4; i++) { v[i] = xr[tid + i * 256]; s += v[i]; }
  __shared__ float red[8];
#pragma unroll
  for (int o = 32; o; o >>= 1) s += __shfl_xor(s, o, 64);
  const int wv = tid >> 6, ln = tid & 63;
  if (!ln) red[wv] = s;
  __syncthreads();
  float mean = (red[0] + red[1] + red[2] + red[3]) * (1.f / 1024.f);
  float s2 = 0.f;
#pragma unroll
  for (int i = 0; i < 4; i++) { float d = v[i] - mean; s2 += d * d; }
#pragma unroll
  for (int o = 32; o; o >>= 1) s2 += __shfl_xor(s2, o, 64);
  if (!ln) red[4 + wv] = s2;
  __syncthreads();
  float var = (red[4] + red[5] + red[6] + red[7]) * (1.f / 1024.f);
  float rstd = rsqrtf(var + 1e-5f);
#pragma unroll
  for (int i = 0; i < 4; i++) {
    int c = tid + i * 256;
    out[(size_t)row * D_ + c] = f2bf((v[i] - mean) * rstd * w[c] + bb[c]);
  }
}

// FFN2 split-K combine: out = out(z1 partial) + P(z0 partial) + resid + bias
__global__ __launch_bounds__(256) void ffn2red_kernel(float* __restrict__ out,
                                                      const float* __restrict__ P,
                                                      const float* __restrict__ resid,
                                                      const float* __restrict__ bias) {
  const size_t i = ((size_t)blockIdx.x * 256 + threadIdx.x) * 4;
  f4_t a  = *(const f4_t*)&out[i];
  f4_t p  = *(const f4_t*)&P[i];
  f4_t rr = *(const f4_t*)&resid[i];
  f4_t bb = *(const f4_t*)&bias[(int)(i & 1023)];
  *(f4_t*)&out[i] = a + p + rr + bb;
}

// ---------------- GEMM 128x128 (proven m97 structure) ----------------
// Used for the Wo GEMM (N=1024, K=1024). T1 XCD-bijective block swizzle
// (nwg = 512, % 8 == 0).
template <int EPI>
__global__ __launch_bounds__(256) void gemm_bt(const unsigned short* __restrict__ A,
                                               const unsigned short* __restrict__ Bt,
                                               const float* __restrict__ bias,
                                               const float* __restrict__ resid,
                                               unsigned short* __restrict__ outb,
                                               float* __restrict__ outf,
                                               int Ndim, int Kdim) {
  __shared__ __align__(16) unsigned short Asmem[4096];   // [128][32]
  __shared__ __align__(16) unsigned short Bsmem[4096];   // [128][32]
  const int tid = threadIdx.x;
  const int wave = tid >> 6, lane = tid & 63;
  const int quad = lane >> 4, l16 = lane & 15;
  const int wm = wave >> 1, wn = wave & 1;

  // XCD-bijective block swizzle
  const int gx = gridDim.x;
  const int nwg = gx * (int)gridDim.y;
  const int lin = (int)blockIdx.y * gx + (int)blockIdx.x;
  const int swz = (lin & 7) * (nwg >> 3) + (lin >> 3);
  const int m0 = (swz / gx) * 128, n0 = (swz % gx) * 128;

  const f4_t fzero = {0.f, 0.f, 0.f, 0.f};
  f4_t acc[4][4];
#pragma unroll
  for (int i = 0; i < 4; i++)
#pragma unroll
    for (int j = 0; j < 4; j++) acc[i][j] = fzero;

  const int rowA = tid >> 2;            // 0..63
  const int kp = (tid & 3) * 8;         // 0,8,16,24

  for (int k0 = 0; k0 < Kdim; k0 += 32) {
    __syncthreads();
#pragma unroll
    for (int r = 0; r < 2; r++) {
      const int row = r * 64 + rowA;
      const int e = row * 32 + kp;
      async16(A  + (size_t)(m0 + row) * Kdim + k0 + kp, &Asmem[e]);
      async16(Bt + (size_t)(n0 + row) * Kdim + k0 + kp, &Bsmem[e]);
    }
    __syncthreads();

    bf8_t a[4], b[4];
#pragma unroll
    for (int i = 0; i < 4; i++) {
      a[i] = *(const bf8_t*)&Asmem[(wm * 64 + i * 16 + l16) * 32 + quad * 8];
      b[i] = *(const bf8_t*)&Bsmem[(wn * 64 + i * 16 + l16) * 32 + quad * 8];
    }
#pragma unroll
    for (int i = 0; i < 4; i++)
#pragma unroll
      for (int j = 0; j < 4; j++)
        acc[i][j] = mfma32(a[i], b[j], acc[i][j]);
  }

#pragma unroll
  for (int i = 0; i < 4; i++) {
#pragma unroll
    for (int j = 0; j < 4; j++) {
#pragma unroll
      for (int r = 0; r < 4; r++) {
        const int m = m0 + wm * 64 + i * 16 + quad * 4 + r;
        const int n = n0 + wn * 64 + j * 16 + l16;
        float v = acc[i][j][r] + bias[n];
        if constexpr (EPI == 2) v = 0.5f * v * (1.f + erff(v * 0.70710678118654752f));
        if constexpr (EPI == 1) {
          v += resid[(size_t)m * Ndim + n];
          outf[(size_t)m * Ndim + n] = v;
        } else {
          outb[(size_t)m * Ndim + n] = f2bf(v);
        }
      }
    }
  }
}

// ---------------- GEMM 256x256, counted-wait overlap (v3.1) ----------------
// 256x256 tile, BK=64, 8 waves (2M x 4N), per-wave 128x64 output (8x4 frags).
// Per K-tile: issue 12 ks0 ds_reads | 12 ks1 ds_reads -> 32 ks0 MFMAs (counted
// lgkmcnt: ks1's LDS drain overlaps the ks0 burst) -> lgkmcnt(0)+barrier ->
// stage full tile t+2 into buf t&1 -> 32 ks1 MFMAs -> counted vmcnt(8) ->
// barrier. 2 barriers/K-tile.
// v3.1: sched_barrier(0) fences pin this order. Round-5's build proved the
// schedule is codegen-fragile (identical source, co-compiled attn change ->
// MfmaUtil 24->16, +48% time): the scheduler either interleaved ks0/ks1 read
// issue (auto-waitcnt then drains all 24 before MFMA #1) or sank STAGE_FULL
// below the ks1 MFMAs (prefetch late -> exposed HBM latency). The fences make
// the counted-wait overlap order-robust.
template <int EPI>
__global__ __launch_bounds__(512, 2) void gemm256(const unsigned short* __restrict__ A,
                                                  const unsigned short* __restrict__ Bt,
                                                  const float* __restrict__ bias,
                                                  const float* __restrict__ resid,
                                                  unsigned short* __restrict__ outb,
                                                  float* __restrict__ outf,
                                                  float* __restrict__ outf2,
                                                  unsigned short* __restrict__ vTout,
                                                  int Ndim, int Kdim, int Kstride) {
  __shared__ __align__(16) unsigned short Asm[32768];   // [2 buf][256 rows][64 k]
  __shared__ __align__(16) unsigned short Bsm[32768];
  const int tid = threadIdx.x;
  const int wave = tid >> 6, lane = tid & 63;
  const int quad = lane >> 4, l16 = lane & 15;
  const int wm = wave >> 2, wn = wave & 3;

  // XCD-bijective block swizzle over (x,y); z is the K-split index
  const int gx = gridDim.x;
  const int nwg = gx * (int)gridDim.y;
  const int lin = (int)blockIdx.y * gx + (int)blockIdx.x;
  const int swz = (lin & 7) * (nwg >> 3) + (lin >> 3);
  const int m0 = (swz / gx) * 256, n0 = (swz % gx) * 256;
  const int kz = (int)blockIdx.z * Kdim;

  const int NT = Kdim >> 6;
  const int srow = lane >> 3, schk = lane & 7;   // stage: lane = 8*subrow + chunk

#define STAGE_A(t, row0) do {                                               \
    const int r_ = (row0) + srow;                                           \
    async16(A + (size_t)(m0 + r_) * Kstride + kz + (t) * 64 +               \
                ((schk ^ (r_ & 7)) << 3),                                   \
            &Asm[(((t) & 1) << 14) + ((row0) << 6)]); } while (0)
#define STAGE_B(t, row0) do {                                               \
    const int r_ = (row0) + srow;                                           \
    async16(Bt + (size_t)(n0 + r_) * Kstride + kz + (t) * 64 +              \
                 ((schk ^ (r_ & 7)) << 3),                                  \
            &Bsm[(((t) & 1) << 14) + ((row0) << 6)]); } while (0)
#define STAGE_FULL(t) do {                                                  \
    STAGE_A(t, wave * 8);       STAGE_A(t, 64 + wave * 8);                  \
    STAGE_A(t, 128 + wave * 8); STAGE_A(t, 192 + wave * 8);                 \
    STAGE_B(t, wave * 8);       STAGE_B(t, 64 + wave * 8);                  \
    STAGE_B(t, 128 + wave * 8); STAGE_B(t, 192 + wave * 8); } while (0)

#define AFR(bo, row, s) \
  (*(const bf8_t*)&Asm[(bo) + ((row) << 6) + ((((s) * 4 + quad) ^ ((row) & 7)) << 3)])
#define BFR(bo, row, s) \
  (*(const bf8_t*)&Bsm[(bo) + ((row) << 6) + ((((s) * 4 + quad) ^ ((row) & 7)) << 3)])

  const f4_t fzero = {0.f, 0.f, 0.f, 0.f};
  f4_t acc[8][4];
#pragma unroll
  for (int i = 0; i < 8; i++)
#pragma unroll
    for (int j = 0; j < 4; j++) acc[i][j] = fzero;

  STAGE_FULL(0);
  STAGE_FULL(1);
  asm volatile("s_waitcnt vmcnt(8)" ::: "memory");
  __builtin_amdgcn_s_barrier();
  SBAR();

  const int ar0 = wm << 7;   // wave A base row (local)
  const int br0 = wn << 6;   // wave B base row (local)

  for (int t = 0; t < NT; ++t) {
    const int bo = (t & 1) << 14;
    const bool pf = (t + 2) < NT;
    const int t2 = t + 2;
    bf8_t a0[8], b0[4], a1[8], b1[4];

    // ks0 reads first (the 12 the first MFMA group waits on)...
#pragma unroll
    for (int i = 0; i < 8; i++) a0[i] = AFR(bo, ar0 + i * 16 + l16, 0);
#pragma unroll
    for (int j = 0; j < 4; j++) b0[j] = BFR(bo, br0 + j * 16 + l16, 0);
    SBAR();   // ...pinned before the ks1 reads: counted waits stay >= 12
#pragma unroll
    for (int i = 0; i < 8; i++) a1[i] = AFR(bo, ar0 + i * 16 + l16, 1);
#pragma unroll
    for (int j = 0; j < 4; j++) b1[j] = BFR(bo, br0 + j * 16 + l16, 1);
    asm volatile("s_waitcnt lgkmcnt(12)" ::: "memory");   // ks0 landed; ks1 in flight
    SBAR();

    // ks0: 32 MFMAs; ks1's 12 reads drain underneath
    __builtin_amdgcn_s_setprio(1);
#pragma unroll
    for (int i = 0; i < 8; i++)
#pragma unroll
      for (int j = 0; j < 4; j++)
        acc[i][j] = mfma32(a0[i], b0[j], acc[i][j]);
    __builtin_amdgcn_s_setprio(0);
    SBAR();

    // all my reads retired; barrier -> every wave done reading buf bo
    asm volatile("s_waitcnt lgkmcnt(0)" ::: "memory");
    __builtin_amdgcn_s_barrier();

    // overwrite buf bo with tile t+2 while ks1 computes from registers;
    // issue pinned BEFORE the MFMA burst so prefetch overlaps it
    if (pf) STAGE_FULL(t2);
    SBAR();

    __builtin_amdgcn_s_setprio(1);
#pragma unroll
    for (int i = 0; i < 8; i++)
#pragma unroll
      for (int j = 0; j < 4; j++)
        acc[i][j] = mfma32(a1[i], b1[j], acc[i][j]);
    __builtin_amdgcn_s_setprio(0);
    SBAR();

    // counted: leave t+2's 8 loads in flight, ensure t+1's are landed
    if (pf) asm volatile("s_waitcnt vmcnt(8)" ::: "memory");
    else    asm volatile("s_waitcnt vmcnt(0)" ::: "memory");
    __builtin_amdgcn_s_barrier();
    SBAR();
  }

#undef STAGE_A
#undef STAGE_B
#undef STAGE_FULL
#undef AFR
#undef BFR

  // ---------------- epilogues ----------------
  if (EPI == 0 && n0 >= 2048) {
    // V region -> vT[(b*16+h)*64+e][ (s&~63) + g(s&63) ], 4 consecutive t per lane
    const int bb2 = m0 >> 11;                      // batch (tile never crosses)
    const int sb64 = (m0 & 2047) + (wm << 7);      // 64-aligned base
#pragma unroll
    for (int mi = 0; mi < 8; mi++) {
      const int i4 = mi & 3;
      const int g0 = (i4 & 2) * 16 + 8 * quad + 4 * (i4 & 1);
      const int sbase = sb64 + (mi >> 2) * 64 + g0;
#pragma unroll
      for (int nj = 0; nj < 4; nj++) {
        const int n = n0 + wn * 64 + nj * 16 + l16;
        const int ef = n - 2048;
        const int hh = ef >> 6, e = ef & 63;
        const float bsv = bias[n];
        uint2 wq;
        wq.x = pk_bf16(acc[mi][nj][0] + bsv, acc[mi][nj][1] + bsv);
        wq.y = pk_bf16(acc[mi][nj][2] + bsv, acc[mi][nj][3] + bsv);
        *(uint2*)&vTout[(size_t)((bb2 * 16 + hh) * 64 + e) * S_ + sbase] = wq;
      }
    }
    return;
  }

  float* const pdst = (EPI == 3) ? (blockIdx.z ? outf2 : outf) : outf;
  const float sc = (EPI == 0 && n0 < 1024) ? QSC : 1.f;
#pragma unroll
  for (int mi = 0; mi < 8; mi++) {
#pragma unroll
    for (int nj = 0; nj < 4; nj++) {
      const int n = n0 + wn * 64 + nj * 16 + l16;
      const float bs = (EPI == 3) ? 0.f : bias[n];
#pragma unroll
      for (int r = 0; r < 4; r++) {
        const int m = m0 + wm * 128 + mi * 16 + quad * 4 + r;
        float v = acc[mi][nj][r] + bs;
        if constexpr (EPI == 0) v *= sc;
        if constexpr (EPI == 2) v = 0.5f * v * (1.f + erff(v * 0.70710678118654752f));
        if constexpr (EPI == 1) {
          v += resid[(size_t)m * Ndim + n];
          outf[(size_t)m * Ndim + n] = v;
        } else if constexpr (EPI == 3) {
          pdst[(size_t)m * Ndim + n] = v;
        } else {
          outb[(size_t)m * Ndim + n] = f2bf(v);
        }
      }
    }
  }
}

// ---------------- flash attention (v2: dbuf K/V + counted vmcnt) ----------------
// 256 threads (4 waves), 128 q-rows/block; wave owns 32 s as 2x16 blocks.
// S^T = mfma(A=K, B=Q) -> P exits QK^T in PV B-operand layout -> PV pure mfma32.
// K/V double-buffered in LDS (72 KB total, 2 blocks/CU); per tile:
// raw-barrier -> stage tile t+1 (8 async16) -> counted vmcnt(8) -> raw-barrier
// -> compute tile t. Mask -> bias table precomputed in LDS once. XCD-chunked
// block swizzle: each XCD gets 8 consecutive bh (all 16 q-blocks).

__global__ __launch_bounds__(256, 2) void attn_kernel(const unsigned short* __restrict__ qkv,
                                                      const unsigned short* __restrict__ vT,
                                                      const int* __restrict__ maskp,
                                                      unsigned short* __restrict__ attended) {
  const int tid = threadIdx.x, wv = tid >> 6, lane = tid & 63;
  const int quad = lane >> 4, l16 = lane & 15;

  // XCD-chunked swizzle (bijective on 1024 blocks): XCD x = lin%8 owns virt
  // [x*128, x*128+128) = 8 bh x 16 q-blocks, q-block fastest.
  const int lin = (int)blockIdx.y * (int)gridDim.x + (int)blockIdx.x;
  const int virt = (lin & 7) * 128 + (lin >> 3);
  const int q0 = (virt & 15) * 128;
  const int bh = virt >> 4, b = bh >> 4, h = bh & 15;

  __shared__ __align__(16) unsigned short KsmF[16384];   // [2 buf][128 t][64 e]
  __shared__ __align__(16) unsigned short VsmF[16384];   // [2 buf][64 e][128 t]
  __shared__ float biasf[2048];                          // mask bias, whole row

  // mask -> bias floats once (2048 ints, 8 per thread)
  {
    const int4 mk0 = *(const int4*)&maskp[b * S_ + tid * 8];
    const int4 mk1 = *(const int4*)&maskp[b * S_ + tid * 8 + 4];
    f4_t bv0, bv1;
    bv0[0] = mk0.x ? 0.f : -8e9f; bv0[1] = mk0.y ? 0.f : -8e9f;
    bv0[2] = mk0.z ? 0.f : -8e9f; bv0[3] = mk0.w ? 0.f : -8e9f;
    bv1[0] = mk1.x ? 0.f : -8e9f; bv1[1] = mk1.y ? 0.f : -8e9f;
    bv1[2] = mk1.z ? 0.f : -8e9f; bv1[3] = mk1.w ? 0.f : -8e9f;
    *(f4_t*)&biasf[tid * 8] = bv0;
    *(f4_t*)&biasf[tid * 8 + 4] = bv1;
  }

// stage K/V tile it into buffer cb: 8 async16 per thread, linear LDS dest,
// inverse-swizzled global source (chunk ^ row&7).
#define STAGE_T(it, cb) do {                                                   \
    _Pragma("unroll")                                                          \
    for (int r_ = 0; r_ < 4; r_++) {                                           \
      const int cc = r_ * 256 + tid;                                           \
      const int krow = cc >> 3, kc = (cc & 7) ^ (krow & 7);                    \
      async16(qkv + (size_t)(b * S_ + (it) * 128 + krow) * 3072 + 1024 +       \
                  h * 64 + kc * 8,                                             \
              &KsmF[((cb) << 13) + cc * 8]);                                   \
      const int e_ = cc >> 4, hf = (cc >> 3) & 1, vc = (cc & 7) ^ (e_ & 7);    \
      async16(vT + (size_t)(bh * 64 + e_) * S_ + (it) * 128 + hf * 64 +        \
                  vc * 8,                                                      \
              &VsmF[((cb) << 13) + cc * 8]);                                   \
    } } while (0)

  // Q fragments straight from global (one-time; B-operand layout k=quad*8+j)
  bf8_t aq[2][2];
#pragma unroll
  for (int sb = 0; sb < 2; sb++) {
    const unsigned short* qrow =
        qkv + (size_t)(b * S_ + q0 + wv * 32 + sb * 16 + l16) * 3072 + h * 64;
    aq[sb][0] = *(const bf8_t*)(qrow + quad * 8);
    aq[sb][1] = *(const bf8_t*)(qrow + 32 + quad * 8);
  }

  const bf8_t ones8 = {0x3F80, 0x3F80, 0x3F80, 0x3F80, 0x3F80, 0x3F80, 0x3F80, 0x3F80};
  const f4_t fzero = {0.f, 0.f, 0.f, 0.f};
  f4_t o[2][4], lacc[2];
#pragma unroll
  for (int sb = 0; sb < 2; sb++) {
    lacc[sb] = fzero;
#pragma unroll
    for (int ee = 0; ee < 4; ee++) o[sb][ee] = fzero;
  }

  // prologue: stage tile 0; bias writes visible after lgkmcnt(0)+barrier.
  STAGE_T(0, 0);
  asm volatile("s_waitcnt lgkmcnt(0)" ::: "memory");
  __builtin_amdgcn_s_barrier();

  for (int it = 0; it < S_ / 128; ++it) {
    const int cb = it & 1;
    // all waves done reading buf cb^1 (tile it-1) -> safe to overwrite
    __builtin_amdgcn_s_barrier();
    if (it + 1 < S_ / 128) {
      STAGE_T(it + 1, cb ^ 1);
      asm volatile("s_waitcnt vmcnt(8)" ::: "memory");   // tile it landed; t+1 in flight
    } else {
      asm volatile("s_waitcnt vmcnt(0)" ::: "memory");
    }
    __builtin_amdgcn_s_barrier();   // every wave's tile-it loads landed

#pragma unroll
    for (int th = 0; th < 2; th++) {
      // S^T: sf[sb][jj][r] = score^T[t=th*64+16jj+4quad+r][s=block+l16] + maskbias
      f4_t sf[2][4];
#pragma unroll
      for (int jj = 0; jj < 4; jj++) {
        f4_t bi = *(const f4_t*)&biasf[it * 128 + th * 64 + jj * 16 + quad * 4];
        sf[0][jj] = bi;
        sf[1][jj] = bi;
      }
      __builtin_amdgcn_s_setprio(1);
#pragma unroll
      for (int jj = 0; jj < 4; jj++) {
        const int krow = th * 64 + jj * 16 + l16, sk = krow & 7;
        bf8_t kf0 = *(const bf8_t*)&KsmF[(cb << 13) + krow * 64 + ((quad ^ sk) << 3)];
        bf8_t kf1 = *(const bf8_t*)&KsmF[(cb << 13) + krow * 64 + (((quad + 4) ^ sk) << 3)];
        sf[0][jj] = mfma32(kf0, aq[0][0], sf[0][jj]);
        sf[0][jj] = mfma32(kf1, aq[0][1], sf[0][jj]);
        sf[1][jj] = mfma32(kf0, aq[1][0], sf[1][jj]);
        sf[1][jj] = mfma32(kf1, aq[1][1], sf[1][jj]);
      }
      __builtin_amdgcn_s_setprio(0);

      // p = exp2(sf); pack straight into K=32 B-frags
      bf8_t pp[2][2];
#pragma unroll
      for (int sb = 0; sb < 2; sb++) {
#pragma unroll
        for (int h2 = 0; h2 < 2; h2++) {
          float p0 = EXP2F(sf[sb][2 * h2][0]),     p1 = EXP2F(sf[sb][2 * h2][1]);
          float p2 = EXP2F(sf[sb][2 * h2][2]),     p3 = EXP2F(sf[sb][2 * h2][3]);
          float p4 = EXP2F(sf[sb][2 * h2 + 1][0]), p5 = EXP2F(sf[sb][2 * h2 + 1][1]);
          float p6 = EXP2F(sf[sb][2 * h2 + 1][2]), p7 = EXP2F(sf[sb][2 * h2 + 1][3]);
          pp[sb][h2] = upk8(pk_bf16(p0, p1), pk_bf16(p2, p3),
                            pk_bf16(p4, p5), pk_bf16(p6, p7));
        }
        lacc[sb] = mfma32(ones8, pp[sb][0], lacc[sb]);
        lacc[sb] = mfma32(ones8, pp[sb][1], lacc[sb]);
      }

      // O^T += V^T x P^T: pure K=32 MFMAs, V-frags single b128 (reused across sb)
      __builtin_amdgcn_s_setprio(1);
#pragma unroll
      for (int ee = 0; ee < 4; ee++) {
        const int vrow = ee * 16 + l16, sv = vrow & 7;
#pragma unroll
        for (int h2 = 0; h2 < 2; h2++) {
          bf8_t vf = *(const bf8_t*)&VsmF[(cb << 13) + vrow * 128 +
                                          (((4 * h2 + quad) ^ sv) << 3)
                                          + th * 64];
          o[0][ee] = mfma32(vf, pp[0][h2], o[0][ee]);
          o[1][ee] = mfma32(vf, pp[1][h2], o[1][ee]);
        }
      }
      __builtin_amdgcn_s_setprio(0);
    }
  }

#undef STAGE_T

  float linv[2];
#pragma unroll
  for (int sb = 0; sb < 2; sb++) linv[sb] = 1.f / lacc[sb][0];

  // transpose O^T -> row-major via LDS overlay (pad 72), coalesced 16-B stores
  __syncthreads();                       // last tile's readers done before overlay
#pragma unroll
  for (int sb = 0; sb < 2; sb++) {
    int srow = wv * 32 + sb * 16 + l16;
#pragma unroll
    for (int ee = 0; ee < 4; ee++) {
      unsigned w0 = pk_bf16(o[sb][ee][0] * linv[sb], o[sb][ee][1] * linv[sb]);
      unsigned w1 = pk_bf16(o[sb][ee][2] * linv[sb], o[sb][ee][3] * linv[sb]);
      uint2 wq; wq.x = w0; wq.y = w1;
      *(uint2*)&KsmF[srow * 72 + ee * 16 + quad * 4] = wq;
    }
  }
  __syncthreads();
#pragma unroll
  for (int it = 0; it < 4; it++) {
    int row = it * 32 + (tid >> 3), e0 = (tid & 7) * 8;
    bf8_t v = *(const bf8_t*)&KsmF[row * 72 + e0];
    *(bf8_t*)&attended[(size_t)(b * S_ + q0 + row) * D_ + h * 64 + e0] = v;
  }
}

// ---------------- launcher ----------------

extern "C" void kernel_launch(void* const* d_in, const int* in_sizes, int n_in,
                              void* d_out, int out_size, void* d_ws, size_t ws_size,
                              hipStream_t stream) {
  const float* state = (const float*)d_in[0];
  const int*   maskp = (const int*)d_in[1];
  const float* ln1w  = (const float*)d_in[2];
  const float* ln1b  = (const float*)d_in[3];
  const float* Wq    = (const float*)d_in[4];
  const float* bq    = (const float*)d_in[5];
  const float* Wk    = (const float*)d_in[6];
  const float* bk    = (const float*)d_in[7];
  const float* Wv    = (const float*)d_in[8];
  const float* bv    = (const float*)d_in[9];
  const float* Wo    = (const float*)d_in[10];
  const float* bo    = (const float*)d_in[11];
  const float* ln2w  = (const float*)d_in[12];
  const float* ln2b  = (const float*)d_in[13];
  const float* W1    = (const float*)d_in[14];
  const float* b1    = (const float*)d_in[15];
  const float* W2    = (const float*)d_in[16];
  const float* b2    = (const float*)d_in[17];

  // workspace carve-up (total ~136 MiB).
  // {hidden, WqkvT, WoT, W1T} form a contiguous 32 MiB block dead by FFN2
  // time -> aliased as the split-K f32 partial buffer P. ff1 aliases the
  // dead qkv+vT region (64 MiB).
  char* w = (char*)d_ws;
  unsigned short* hidden = (unsigned short*)w; w += (size_t)M_ * D_ * 2;      // 16 MiB
  unsigned short* WqkvT  = (unsigned short*)w; w += (size_t)3072 * D_ * 2;    //  6 MiB
  unsigned short* WoT    = (unsigned short*)w; w += (size_t)D_ * D_ * 2;      //  2 MiB
  unsigned short* W1T    = (unsigned short*)w; w += (size_t)DF_ * D_ * 2;     //  8 MiB
  unsigned short* qkv    = (unsigned short*)w; w += (size_t)M_ * 3072 * 2;    // 48 MiB
  unsigned short* vT     = (unsigned short*)w; w += (size_t)M_ * D_ * 2;      // 16 MiB
  float*          outp   = (float*)w;          w += (size_t)M_ * D_ * 4;      // 32 MiB
  unsigned short* W2T    = (unsigned short*)w; w += (size_t)D_ * DF_ * 2;     //  8 MiB
  float*          bqkv   = (float*)w;          w += 3072 * 4;
  unsigned short* ff1    = qkv;                // 64 MiB alias (qkv+vT dead before FFN1)
  float*          Pbuf   = (float*)hidden;     // 32 MiB alias (dead before FFN2)

  // weight prep
  qkvpack_kernel<<<dim3(32, 2, 48), 256, 0, stream>>>(Wq, Wk, Wv, WqkvT);
  wtrans_kernel<<<dim3(32, 32), 256, 0, stream>>>(Wo, WoT, D_, D_);
  wtrans_kernel<<<dim3(32, 128), 256, 0, stream>>>(W1, W1T, D_, DF_);
  wtrans_kernel<<<dim3(128, 32), 256, 0, stream>>>(W2, W2T, DF_, D_);
  biaspack_kernel<<<12, 256, 0, stream>>>(bq, bk, bv, bqkv);

  // attention block (V transposed into vT by the QKV epilogue)
  ln_kernel<<<M_, 256, 0, stream>>>(state, ln1w, ln1b, hidden);
  gemm256<0><<<dim3(3072 / 256, M_ / 256), 512, 0, stream>>>(
      hidden, WqkvT, bqkv, nullptr, qkv, nullptr, nullptr, vT, 3072, D_, D_);
  attn_kernel<<<dim3(S_ / 128, B_ * H_), 256, 0, stream>>>(qkv, vT, maskp, hidden);
  gemm_bt<1><<<dim3(D_ / 128, M_ / 128), 256, 0, stream>>>(hidden, WoT, bo, state,
                                                           nullptr, outp, D_, D_);
  // FFN block
  ln_kernel<<<M_, 256, 0, stream>>>(outp, ln2w, ln2b, hidden);
  gemm256<2><<<dim3(DF_ / 256, M_ / 256), 512, 0, stream>>>(
      hidden, W1T, b1, nullptr, ff1, nullptr, nullptr, nullptr, DF_, D_, D_);
  // FFN2: split-K=2 over z (full-GPU 256 blocks); z0 -> Pbuf, z1 -> d_out (raw),
  // then combine with resid + bias.
  gemm256<3><<<dim3(D_ / 256, M_ / 256, 2), 512, 0, stream>>>(
      ff1, W2T, nullptr, nullptr, nullptr, Pbuf, (float*)d_out, nullptr,
      D_, DF_ / 2, DF_);
  ffn2red_kernel<<<(M_ * D_) / 1024, 256, 0, stream>>>((float*)d_out, Pbuf, outp, b2);
}